// Round 13
// baseline (231.109 us; speedup 1.0000x reference)
//
#include <hip/hip_runtime.h>
#include <hip/hip_bf16.h>

#define N_NODES 50000
#define N_EDGES 800000
#define D 64
#define B 64
#define HL 128
#define OUT 32

#define CAP 64          // max in-degree capacity (Poisson(16): P(>=64) ~ 1e-18)
#define STP 72          // LDS transform tile row stride (ushorts)
#define PK 8            // pool partial blocks per graph
#define ZROW N_NODES    // sentinel index (u16-safe: 50000 < 65536)

#define BINS 196        // ceil(N_NODES/256): coarse bins of 256 nodes (dst>>8)
#define EPB 2048        // edges per block in binA
#define LCAP 48         // per-(block,bin) LDS staging cap
#define BCAP 4608       // per-bin global region cap (mean 4082)

typedef __attribute__((ext_vector_type(8))) short          short8;
typedef __attribute__((ext_vector_type(8))) unsigned short ushort8_t;
typedef __attribute__((ext_vector_type(4))) float          floatx4;

// bf16 helpers (RNE pack, cheap unpack)
__device__ __forceinline__ unsigned short f2bf(float f)
{
    unsigned u = __float_as_uint(f);
    u = (u + 0x7FFFu + ((u >> 16) & 1u)) >> 16;
    return (unsigned short)u;
}
__device__ __forceinline__ float bf2f(unsigned short s)
{
    return __uint_as_float(((unsigned)s) << 16);
}

// ---------------------------------------------------------------------------
// cvt: x (fp32) -> bf16 table; blocks < 64 also convert the 4 MLP weight
// matrices; block 64 zeroes bincnt + the xb/h1 sentinel zero rows.
// ---------------------------------------------------------------------------
__global__ __launch_bounds__(256) void cvt_kernel(
    const float* __restrict__ x, unsigned short* __restrict__ xb,
    const float* __restrict__ w1, const float* __restrict__ w2,
    const float* __restrict__ w3, const float* __restrict__ w4,
    unsigned short* __restrict__ wb,
    int* __restrict__ bincnt,
    unsigned short* __restrict__ h1)
{
    int i = blockIdx.x * 256 + threadIdx.x;          // i < N*D/4
    const float4 v = reinterpret_cast<const float4*>(x)[i];
    ushort4 o;
    o.x = f2bf(v.x); o.y = f2bf(v.y); o.z = f2bf(v.z); o.w = f2bf(v.w);
    reinterpret_cast<ushort4*>(xb)[i] = o;

    if (blockIdx.x < 64) {                           // 64*256 = 4*4096
        int j = blockIdx.x * 256 + threadIdx.x;
        int m = j >> 12, off = j & 4095;
        const float* src = (m == 0) ? w1 : (m == 1) ? w2 : (m == 2) ? w3 : w4;
        wb[j] = f2bf(src[off]);
    }
    if (blockIdx.x == 64) {
        int t = threadIdx.x;
        bincnt[t] = 0;
        if (t < D) {                                 // sentinel zero rows
            xb[(size_t)ZROW * D + t] = 0;
            h1[(size_t)ZROW * D + t] = 0;
        }
    }
}

// ---------------------------------------------------------------------------
// Adjacency build phase A: bin edges by dst>>8 via LDS staging, flush
// contiguous per-bin segments. Entry packing: s (16b) | dst&255 (8b) << 16.
// ---------------------------------------------------------------------------
__global__ __launch_bounds__(256) void binA_kernel(
    const int* __restrict__ ei, int* __restrict__ bincnt,
    unsigned* __restrict__ binbuf)
{
    __shared__ int      lcnt[BINS];
    __shared__ int      gbase[BINS];
    __shared__ unsigned lbuf[BINS * LCAP];   // 37.6 KB

    int t = threadIdx.x;
    if (t < BINS) lcnt[t] = 0;
    __syncthreads();

    int base = blockIdx.x * EPB;
#pragma unroll
    for (int i = 0; i < EPB / 256; ++i) {
        int e = base + i * 256 + t;
        if (e < N_EDGES) {
            int s = ei[e];
            int d = ei[N_EDGES + e];
            int bin = d >> 8;
            unsigned pk = (unsigned)s | ((unsigned)(d & 255) << 16);
            int p = atomicAdd(&lcnt[bin], 1);
            if (p < LCAP) {
                lbuf[bin * LCAP + p] = pk;
            } else {                          // statistically never
                int q = atomicAdd(&bincnt[bin], 1);
                if (q < BCAP) binbuf[bin * BCAP + q] = pk;
            }
        }
    }
    __syncthreads();

    if (t < BINS) {
        int m = lcnt[t]; m = (m < LCAP) ? m : LCAP;
        gbase[t] = (m > 0) ? atomicAdd(&bincnt[t], m) : 0;
    }
    __syncthreads();

    int wv = t >> 6, lane = t & 63;
    for (int b = wv; b < BINS; b += 4) {
        int m = lcnt[b]; m = (m < LCAP) ? m : LCAP;
        int gb = gbase[b];
        for (int j = lane; j < m; j += 64)
            if (gb + j < BCAP) binbuf[b * BCAP + gb + j] = lbuf[b * LCAP + j];
    }
}

// ---------------------------------------------------------------------------
// Adjacency build phase B: block per bin (256 nodes). LDS rows pre-filled
// with sentinel ZROW so bucket rows are padded -> branchless gather.
// ---------------------------------------------------------------------------
__global__ __launch_bounds__(256) void binB_kernel(
    const int*      __restrict__ bincnt,
    const unsigned* __restrict__ binbuf,
    int*            __restrict__ cnt,     // [N]
    unsigned short* __restrict__ bucket)  // [N,CAP]
{
    __shared__ int            lc[256];
    __shared__ unsigned short lbkt[256 * CAP];   // 32 KB

    int t = threadIdx.x;
    lc[t] = 0;
    {
        ushort8_t fill = {ZROW, ZROW, ZROW, ZROW, ZROW, ZROW, ZROW, ZROW};
        for (int idx = t; idx < 256 * CAP / 8; idx += 256)
            reinterpret_cast<ushort8_t*>(lbkt)[idx] = fill;
    }
    __syncthreads();

    int bin = blockIdx.x;
    int m = bincnt[bin]; m = (m < BCAP) ? m : BCAP;
    const unsigned* src = binbuf + bin * BCAP;
    for (int j = t; j < m; j += 256) {
        unsigned pk = src[j];
        int dlow = (pk >> 16) & 255;
        int p = atomicAdd(&lc[dlow], 1);
        if (p < CAP) lbkt[dlow * CAP + p] = (unsigned short)(pk & 0xFFFFu);
    }
    __syncthreads();

    int n0 = bin * 256;
    int n = n0 + t;
    if (n < N_NODES) cnt[n] = (lc[t] < CAP) ? lc[t] : CAP;

    for (int idx = t; idx < 256 * 8; idx += 256) {
        int r = idx >> 3, c = idx & 7;
        if (n0 + r < N_NODES)
            *reinterpret_cast<ushort8_t*>(
                bucket + (size_t)(n0 + r) * CAP + c * 8) =
                *reinterpret_cast<const ushort8_t*>(&lbkt[r * CAP + c * 8]);
    }
}

// ---------------------------------------------------------------------------
// Gather, dim-split: one pass covers 32 of the 64 dims for all nodes, so the
// pass working set (one 64B line of each row) is 3.2 MB < 4 MB per-XCD L2.
// Lane layout: 64 lanes = 2 nodes x 32 dims. Each feature-load instruction
// fetches exactly 2 cache lines (same as full-width layout) -> locality win
// at zero instruction cost. Output via nontemporal stores (don't evict the
// table). Branchless rounds with ZROW padding.
// ---------------------------------------------------------------------------
__global__ __launch_bounds__(256) void gather_kernel(
    const unsigned short* __restrict__ feat,   // [N+pad,64] bf16, row ZROW = 0
    const int*            __restrict__ cnt,
    const unsigned short* __restrict__ bucket, // [N,CAP] u16, ZROW-padded
    unsigned short*       __restrict__ outp,   // [N,64] bf16
    int dimoff)                                // 0 or 32
{
    int wv   = threadIdx.x >> 6;
    int lane = threadIdx.x & 63;
    int half = lane >> 5;                      // 0: node A, 1: node B
    int dim  = (lane & 31) + dimoff;
    int n    = (blockIdx.x * 4 + wv) * 2 + half;   // grid exact; N even

    int deg = cnt[n];
    deg = (deg < CAP) ? deg : CAP;
    int rounds = (deg + 15) >> 4;
    const unsigned short* bkt = bucket + (size_t)n * CAP;

    float acc = bf2f(feat[(size_t)n * D + dim]);
    for (int r = 0; r < rounds; ++r) {
        ushort8_t i0 = *reinterpret_cast<const ushort8_t*>(bkt + r * 16);
        ushort8_t i1 = *reinterpret_cast<const ushort8_t*>(bkt + r * 16 + 8);
        float v0 = bf2f(feat[(size_t)i0[0] * D + dim]);
        float v1 = bf2f(feat[(size_t)i0[1] * D + dim]);
        float v2 = bf2f(feat[(size_t)i0[2] * D + dim]);
        float v3 = bf2f(feat[(size_t)i0[3] * D + dim]);
        float v4 = bf2f(feat[(size_t)i0[4] * D + dim]);
        float v5 = bf2f(feat[(size_t)i0[5] * D + dim]);
        float v6 = bf2f(feat[(size_t)i0[6] * D + dim]);
        float v7 = bf2f(feat[(size_t)i0[7] * D + dim]);
        float v8 = bf2f(feat[(size_t)i1[0] * D + dim]);
        float v9 = bf2f(feat[(size_t)i1[1] * D + dim]);
        float va = bf2f(feat[(size_t)i1[2] * D + dim]);
        float vb = bf2f(feat[(size_t)i1[3] * D + dim]);
        float vc = bf2f(feat[(size_t)i1[4] * D + dim]);
        float vd = bf2f(feat[(size_t)i1[5] * D + dim]);
        float ve = bf2f(feat[(size_t)i1[6] * D + dim]);
        float vf = bf2f(feat[(size_t)i1[7] * D + dim]);
        acc += (((v0 + v1) + (v2 + v3)) + ((v4 + v5) + (v6 + v7)))
             + (((v8 + v9) + (va + vb)) + ((vc + vd) + (ve + vf)));
    }
    __builtin_nontemporal_store(f2bf(acc), &outp[(size_t)n * D + dim]);
}

// ---------------------------------------------------------------------------
// MLP via MFMA: out = relu( relu(h @ wA.T + bA) @ wB.T + bB ), bf16 in/out.
// Wave per 16-node tile; weights as B-fragments in VGPRs; inter-GEMM relu
// re-enters A-layout via a per-wave LDS tile (verified m89/m91 layouts).
// ---------------------------------------------------------------------------
__global__ __launch_bounds__(256) void mlp_kernel(
    const unsigned short* __restrict__ feat,   // [N,64] bf16  (gathered h)
    const unsigned short* __restrict__ wAb,    // [64,64] bf16
    const float*          __restrict__ bA,     // [64]
    const unsigned short* __restrict__ wBb,    // [64,64] bf16
    const float*          __restrict__ bB,     // [64]
    unsigned short*       __restrict__ outp)   // [N,64] bf16
{
    __shared__ __align__(16) unsigned short st[4][16 * STP];

    const int wv   = threadIdx.x >> 6;
    const int lane = threadIdx.x & 63;
    const int quad = lane >> 4;
    const int col  = lane & 15;

    const int n0 = (blockIdx.x * 4 + wv) * 16;
    if (n0 >= N_NODES) return;

    float bAl[4], bBl[4];
#pragma unroll
    for (int t = 0; t < 4; ++t) {
        bAl[t] = bA[t * 16 + col];
        bBl[t] = bB[t * 16 + col];
    }

    short8 WA[4][2], WB[4][2];
#pragma unroll
    for (int t = 0; t < 4; ++t)
#pragma unroll
        for (int k = 0; k < 2; ++k) {
            WA[t][k] = *reinterpret_cast<const short8*>(
                wAb + (t * 16 + col) * D + k * 32 + quad * 8);
            WB[t][k] = *reinterpret_cast<const short8*>(
                wBb + (t * 16 + col) * D + k * 32 + quad * 8);
        }

    short8 A0 = *reinterpret_cast<const short8*>(
        feat + (size_t)(n0 + col) * D + 0 * 32 + quad * 8);
    short8 A1 = *reinterpret_cast<const short8*>(
        feat + (size_t)(n0 + col) * D + 1 * 32 + quad * 8);

    unsigned short* stw = &st[wv][0];

    // ---- GEMM 1 + bias + relu -> LDS (A-layout staging) ----
#pragma unroll
    for (int t = 0; t < 4; ++t) {
        floatx4 c = {0.0f, 0.0f, 0.0f, 0.0f};
        c = __builtin_amdgcn_mfma_f32_16x16x32_bf16(A0, WA[t][0], c, 0, 0, 0);
        c = __builtin_amdgcn_mfma_f32_16x16x32_bf16(A1, WA[t][1], c, 0, 0, 0);
#pragma unroll
        for (int r = 0; r < 4; ++r) {
            float v = fmaxf(c[r] + bAl[t], 0.0f);
            stw[(quad * 4 + r) * STP + t * 16 + col] = f2bf(v);
        }
    }

    short8 T0 = *reinterpret_cast<const short8*>(stw + col * STP + 0 * 32 + quad * 8);
    short8 T1 = *reinterpret_cast<const short8*>(stw + col * STP + 1 * 32 + quad * 8);

    // ---- GEMM 2 + bias + relu -> global ----
#pragma unroll
    for (int t = 0; t < 4; ++t) {
        floatx4 c = {0.0f, 0.0f, 0.0f, 0.0f};
        c = __builtin_amdgcn_mfma_f32_16x16x32_bf16(T0, WB[t][0], c, 0, 0, 0);
        c = __builtin_amdgcn_mfma_f32_16x16x32_bf16(T1, WB[t][1], c, 0, 0, 0);
#pragma unroll
        for (int r = 0; r < 4; ++r) {
            float v = fmaxf(c[r] + bBl[t], 0.0f);
            outp[(size_t)(n0 + quad * 4 + r) * D + t * 16 + col] = f2bf(v);
        }
    }
}

// ---------------------------------------------------------------------------
// Pool phase 1: PK blocks per graph write partial sums psum[b][k][64].
// ---------------------------------------------------------------------------
__device__ __forceinline__ int lower_bound_dev(const int* a, int n, int v)
{
    int lo = 0, hi = n;
    while (lo < hi) {
        int m = (lo + hi) >> 1;
        if (a[m] < v) lo = m + 1; else hi = m;
    }
    return lo;
}

__global__ __launch_bounds__(256) void pool_partial_kernel(
    const unsigned short* __restrict__ feat,   // [N,64] bf16
    const int*            __restrict__ batch,  // [N] sorted
    float*                __restrict__ psum)   // [B,PK,64]
{
    int b = blockIdx.x >> 3;          // graph
    int k = blockIdx.x & (PK - 1);    // partial slot
    int start = lower_bound_dev(batch, N_NODES, b);
    int end   = lower_bound_dev(batch, N_NODES, b + 1);

    int d = threadIdx.x & 63;
    int r = threadIdx.x >> 6;         // 0..3

    float acc = 0.0f;
    for (int n = start + k * 4 + r; n < end; n += PK * 4)
        acc += bf2f(feat[(size_t)n * D + d]);

    __shared__ float red[4][D];
    red[r][d] = acc;
    __syncthreads();
    if (r == 0)
        psum[((size_t)b * PK + k) * D + d] =
            red[0][d] + red[1][d] + red[2][d] + red[3][d];
}

// ---------------------------------------------------------------------------
// Head: fold pool partials, single-step LSTM + FC + softmax. Block per graph.
// ---------------------------------------------------------------------------
__device__ __forceinline__ float sigmoidf_(float x) { return 1.0f / (1.0f + expf(-x)); }

__global__ __launch_bounds__(512) void head_kernel(
    const float* __restrict__ psum,   // [B,PK,64]
    const int*   __restrict__ batch,  // [N]
    const float* __restrict__ w_ih,
    const float* __restrict__ w_hh,
    const float* __restrict__ b_ih,
    const float* __restrict__ b_hh,
    const float* __restrict__ fc_w,
    const float* __restrict__ fc_b,
    const float* __restrict__ h0,
    const float* __restrict__ c0,
    float*       __restrict__ out_probs,
    float*       __restrict__ out_h1,
    float*       __restrict__ out_c1)
{
    int b = blockIdx.x;
    int j = threadIdx.x;

    __shared__ float sp[D];
    __shared__ float sh[HL];
    __shared__ float gates[4 * HL];
    __shared__ float sh1[HL];
    __shared__ float slog[OUT];

    if (j < D) {
        int start = lower_bound_dev(batch, N_NODES, b);
        int end   = lower_bound_dev(batch, N_NODES, b + 1);
        float s = 0.0f;
#pragma unroll
        for (int k = 0; k < PK; ++k) s += psum[((size_t)b * PK + k) * D + j];
        sp[j] = s / fmaxf((float)(end - start), 1.0f);
    } else if (j < D + HL) {
        sh[j - D] = h0[b * HL + (j - D)];
    }
    __syncthreads();

    {
        float acc = b_ih[j] + b_hh[j];
#pragma unroll
        for (int k = 0; k < D; ++k)  acc = fmaf(sp[k], w_ih[j * D + k], acc);
#pragma unroll
        for (int k = 0; k < HL; ++k) acc = fmaf(sh[k], w_hh[j * HL + k], acc);
        gates[j] = acc;
    }
    __syncthreads();

    if (j < HL) {
        float ig = gates[j];
        float fg = gates[HL + j];
        float gg = gates[2 * HL + j];
        float og = gates[3 * HL + j];
        float c  = sigmoidf_(fg) * c0[b * HL + j] + sigmoidf_(ig) * tanhf(gg);
        float hv = sigmoidf_(og) * tanhf(c);
        out_c1[b * HL + j] = c;
        out_h1[b * HL + j] = hv;
        sh1[j] = hv;
    }
    __syncthreads();

    if (j < OUT) {
        float a = fc_b[j];
#pragma unroll
        for (int k = 0; k < HL; ++k) a = fmaf(sh1[k], fc_w[j * HL + k], a);
        slog[j] = a;
    }
    __syncthreads();

    if (j < OUT) {
        float m = -1e30f;
#pragma unroll
        for (int k = 0; k < OUT; ++k) m = fmaxf(m, slog[k]);
        float s = 0.0f;
#pragma unroll
        for (int k = 0; k < OUT; ++k) s += expf(slog[k] - m);
        out_probs[b * OUT + j] = expf(slog[j] - m) / s;
    }
}

// ---------------------------------------------------------------------------
extern "C" void kernel_launch(void* const* d_in, const int* in_sizes, int n_in,
                              void* d_out, int out_size, void* d_ws, size_t ws_size,
                              hipStream_t stream)
{
    const float* x     = (const float*)d_in[0];
    const int*   ei    = (const int*)  d_in[1];
    const int*   batch = (const int*)  d_in[2];
    const float* w1    = (const float*)d_in[3];
    const float* b1    = (const float*)d_in[4];
    const float* w2    = (const float*)d_in[5];
    const float* b2    = (const float*)d_in[6];
    const float* w3    = (const float*)d_in[7];
    const float* b3    = (const float*)d_in[8];
    const float* w4    = (const float*)d_in[9];
    const float* b4    = (const float*)d_in[10];
    const float* w_ih  = (const float*)d_in[11];
    const float* w_hh  = (const float*)d_in[12];
    const float* b_ih  = (const float*)d_in[13];
    const float* b_hh  = (const float*)d_in[14];
    const float* fc_w  = (const float*)d_in[15];
    const float* fc_b  = (const float*)d_in[16];
    const float* h0    = (const float*)d_in[17];
    const float* c0    = (const float*)d_in[18];

    // workspace layout (~22 MB); xb/h1 have N+16 rows (row ZROW = 0)
    const size_t NR = (size_t)N_NODES + 16;
    int* bincnt = (int*)d_ws;                                 // 256 ints
    int* cnt    = bincnt + 256;                               // N ints
    unsigned* binbuf = (unsigned*)(cnt + N_NODES);            // BINS*BCAP
    unsigned short* bucket = (unsigned short*)(binbuf + (size_t)BINS * BCAP);
    unsigned short* xb = bucket + (size_t)N_NODES * CAP;      // [NR,64] bf16
    unsigned short* g  = xb + NR * D;                         // [NR,64] gather out
    unsigned short* h1 = g  + NR * D;                         // [NR,64] mlp1 out
    unsigned short* f2 = h1 + NR * D;                         // [NR,64] mlp2 out
    unsigned short* wb = f2 + NR * D;                         // 4 x [64,64] bf16
    float* psum = (float*)(wb + 4 * D * D);                   // [B,PK,64]

    float* out_probs = (float*)d_out;
    float* out_h1    = out_probs + B * OUT;
    float* out_c1    = out_h1 + B * HL;

    const int cb = N_NODES * D / 4 / 256;            // 3125
    const int ab = (N_EDGES + EPB - 1) / EPB;        // 391
    const int gb = N_NODES / 8;                      // 6250 (2 nodes/wave)
    const int mb = (N_NODES / 16 + 3) / 4;           // 782

    // ---- cvt x->bf16 + weight cvt + bincnt + sentinel rows ----
    cvt_kernel<<<cb, 256, 0, stream>>>(x, xb, w1, w2, w3, w4, wb, bincnt, h1);

    // ---- adjacency build: LDS-binned two-phase, ZROW-padded buckets ----
    binA_kernel<<<ab, 256, 0, stream>>>(ei, bincnt, binbuf);
    binB_kernel<<<BINS, 256, 0, stream>>>(bincnt, binbuf, cnt, bucket);

    // ---- layer 1 (2 dim-passes) ----
    gather_kernel<<<gb, 256, 0, stream>>>(xb, cnt, bucket, g, 0);
    gather_kernel<<<gb, 256, 0, stream>>>(xb, cnt, bucket, g, 32);
    mlp_kernel<<<mb, 256, 0, stream>>>(g, wb, b1, wb + 4096, b2, h1);

    // ---- layer 2 (2 dim-passes) ----
    gather_kernel<<<gb, 256, 0, stream>>>(h1, cnt, bucket, g, 0);
    gather_kernel<<<gb, 256, 0, stream>>>(h1, cnt, bucket, g, 32);
    mlp_kernel<<<mb, 256, 0, stream>>>(g, wb + 8192, b3, wb + 12288, b4, f2);

    // ---- pool (two-phase) + head ----
    pool_partial_kernel<<<B * PK, 256, 0, stream>>>(f2, batch, psum);
    head_kernel<<<B, 512, 0, stream>>>(psum, batch, w_ih, w_hh, b_ih, b_hh,
                                       fc_w, fc_b, h0, c0,
                                       out_probs, out_h1, out_c1);
}

// Round 14
// 209.906 us; speedup vs baseline: 1.1010x; 1.1010x over previous
//
#include <hip/hip_runtime.h>
#include <hip/hip_bf16.h>

#define N_NODES 50000
#define N_EDGES 800000
#define D 64
#define B 64
#define HL 128
#define OUT 32

#define CAP 64          // max in-degree capacity (Poisson(16): P(>=64) ~ 1e-18)
#define STP 72          // LDS transform tile row stride (ushorts)
#define ZROW N_NODES    // sentinel index (u16-safe: 50000 < 65536)

#define BINS 196        // ceil(N_NODES/256): coarse bins of 256 nodes (dst>>8)
#define EPB 2048        // edges per block in binA
#define LCAP 48         // per-(block,bin) LDS staging cap
#define BCAP 4608       // per-bin global region cap (mean 4082)

#define AB 391          // binA blocks
#define CB 3125         // cvt blocks (N*D/4/256)

typedef __attribute__((ext_vector_type(8))) short          short8;
typedef __attribute__((ext_vector_type(8))) unsigned short ushort8_t;
typedef __attribute__((ext_vector_type(4))) float          floatx4;

// bf16 helpers (RNE pack, cheap unpack)
__device__ __forceinline__ unsigned short f2bf(float f)
{
    unsigned u = __float_as_uint(f);
    u = (u + 0x7FFFu + ((u >> 16) & 1u)) >> 16;
    return (unsigned short)u;
}
__device__ __forceinline__ float bf2f(unsigned short s)
{
    return __uint_as_float(((unsigned)s) << 16);
}

// ---------------------------------------------------------------------------
// Fused prologue, block-range roles (independent work overlaps in 1 dispatch):
//   [0, AB)        : binA — bin edges by dst>>8 via LDS staging
//   [AB, AB+CB)    : cvt x -> bf16 (first 64 also convert MLP weights)
//   AB+CB          : init — sentinel zero rows + psum zero
// bincnt is zeroed by a prior 1KB memset.
// ---------------------------------------------------------------------------
__global__ __launch_bounds__(256) void fused_pro_kernel(
    const int*   __restrict__ ei,
    int*         __restrict__ bincnt,
    unsigned*    __restrict__ binbuf,
    const float* __restrict__ x, unsigned short* __restrict__ xb,
    const float* __restrict__ w1, const float* __restrict__ w2,
    const float* __restrict__ w3, const float* __restrict__ w4,
    unsigned short* __restrict__ wb,
    unsigned short* __restrict__ h1,
    float*       __restrict__ psum)
{
    __shared__ int      lcnt[BINS];
    __shared__ int      gbase[BINS];
    __shared__ unsigned lbuf[BINS * LCAP];   // 37.6 KB

    int t = threadIdx.x;

    if (blockIdx.x < AB) {
        // ---------------- binA ----------------
        if (t < BINS) lcnt[t] = 0;
        __syncthreads();

        int base = blockIdx.x * EPB;
#pragma unroll
        for (int i = 0; i < EPB / 256; ++i) {
            int e = base + i * 256 + t;
            if (e < N_EDGES) {
                int s = ei[e];
                int d = ei[N_EDGES + e];
                int bin = d >> 8;
                unsigned pk = (unsigned)s | ((unsigned)(d & 255) << 16);
                int p = atomicAdd(&lcnt[bin], 1);
                if (p < LCAP) {
                    lbuf[bin * LCAP + p] = pk;
                } else {                          // statistically never
                    int q = atomicAdd(&bincnt[bin], 1);
                    if (q < BCAP) binbuf[bin * BCAP + q] = pk;
                }
            }
        }
        __syncthreads();

        if (t < BINS) {
            int m = lcnt[t]; m = (m < LCAP) ? m : LCAP;
            gbase[t] = (m > 0) ? atomicAdd(&bincnt[t], m) : 0;
        }
        __syncthreads();

        int wv = t >> 6, lane = t & 63;
        for (int b = wv; b < BINS; b += 4) {
            int m = lcnt[b]; m = (m < LCAP) ? m : LCAP;
            int gb = gbase[b];
            for (int j = lane; j < m; j += 64)
                if (gb + j < BCAP) binbuf[b * BCAP + gb + j] = lbuf[b * LCAP + j];
        }
    } else if (blockIdx.x < AB + CB) {
        // ---------------- cvt ----------------
        int cb = blockIdx.x - AB;
        int i = cb * 256 + t;                    // i < N*D/4
        const float4 v = reinterpret_cast<const float4*>(x)[i];
        ushort4 o;
        o.x = f2bf(v.x); o.y = f2bf(v.y); o.z = f2bf(v.z); o.w = f2bf(v.w);
        reinterpret_cast<ushort4*>(xb)[i] = o;

        if (cb < 64) {                           // 64*256 = 4*4096
            int j = cb * 256 + t;
            int m = j >> 12, off = j & 4095;
            const float* src = (m == 0) ? w1 : (m == 1) ? w2 : (m == 2) ? w3 : w4;
            wb[j] = f2bf(src[off]);
        }
    } else {
        // ---------------- init ----------------
        if (t < D) {                             // sentinel zero rows
            xb[(size_t)ZROW * D + t] = 0;
            h1[(size_t)ZROW * D + t] = 0;
        }
#pragma unroll
        for (int k = 0; k < 16; ++k)             // psum[B*64] = 0
            psum[t * 16 + k] = 0.0f;
    }
}

// ---------------------------------------------------------------------------
// Adjacency build phase B: block per bin (256 nodes). LDS rows pre-filled
// with sentinel ZROW so bucket rows are padded -> branchless gather.
// ---------------------------------------------------------------------------
__global__ __launch_bounds__(256) void binB_kernel(
    const int*      __restrict__ bincnt,
    const unsigned* __restrict__ binbuf,
    int*            __restrict__ cnt,     // [N]
    unsigned short* __restrict__ bucket)  // [N,CAP]
{
    __shared__ int            lc[256];
    __shared__ unsigned short lbkt[256 * CAP];   // 32 KB

    int t = threadIdx.x;
    lc[t] = 0;
    {
        ushort8_t fill = {ZROW, ZROW, ZROW, ZROW, ZROW, ZROW, ZROW, ZROW};
        for (int idx = t; idx < 256 * CAP / 8; idx += 256)
            reinterpret_cast<ushort8_t*>(lbkt)[idx] = fill;
    }
    __syncthreads();

    int bin = blockIdx.x;
    int m = bincnt[bin]; m = (m < BCAP) ? m : BCAP;
    const unsigned* src = binbuf + bin * BCAP;
    for (int j = t; j < m; j += 256) {
        unsigned pk = src[j];
        int dlow = (pk >> 16) & 255;
        int p = atomicAdd(&lc[dlow], 1);
        if (p < CAP) lbkt[dlow * CAP + p] = (unsigned short)(pk & 0xFFFFu);
    }
    __syncthreads();

    int n0 = bin * 256;
    int n = n0 + t;
    if (n < N_NODES) cnt[n] = (lc[t] < CAP) ? lc[t] : CAP;

    for (int idx = t; idx < 256 * 8; idx += 256) {
        int r = idx >> 3, c = idx & 7;
        if (n0 + r < N_NODES)
            *reinterpret_cast<ushort8_t*>(
                bucket + (size_t)(n0 + r) * CAP + c * 8) =
                *reinterpret_cast<const ushort8_t*>(&lbkt[r * CAP + c * 8]);
    }
}

// ---------------------------------------------------------------------------
// Gather (R11 best form): out[n] = x[n] + sum_{j in N(n)} x[j]. Wave per
// node, lane = dim, branchless ceil(deg/16) x 16 unconditional loads.
// ---------------------------------------------------------------------------
__global__ __launch_bounds__(256) void gather_kernel(
    const unsigned short* __restrict__ feat,   // [N+pad,64] bf16, row ZROW = 0
    const int*            __restrict__ cnt,
    const unsigned short* __restrict__ bucket, // [N,CAP] u16, ZROW-padded
    unsigned short*       __restrict__ outp)   // [N,64] bf16
{
    int wv = threadIdx.x >> 6, lane = threadIdx.x & 63;
    int n = blockIdx.x * 4 + wv;               // grid exact: n < N_NODES

    int deg = cnt[n];
    deg = (deg < CAP) ? deg : CAP;
    int rounds = (deg + 15) >> 4;
    const unsigned short* bkt = bucket + (size_t)n * CAP;

    float acc = bf2f(feat[(size_t)n * D + lane]);
    for (int r = 0; r < rounds; ++r) {
        ushort8_t ia = *reinterpret_cast<const ushort8_t*>(bkt + r * 16);
        ushort8_t ib = *reinterpret_cast<const ushort8_t*>(bkt + r * 16 + 8);
        float v0 = bf2f(feat[(size_t)ia[0] * D + lane]);
        float v1 = bf2f(feat[(size_t)ia[1] * D + lane]);
        float v2 = bf2f(feat[(size_t)ia[2] * D + lane]);
        float v3 = bf2f(feat[(size_t)ia[3] * D + lane]);
        float v4 = bf2f(feat[(size_t)ia[4] * D + lane]);
        float v5 = bf2f(feat[(size_t)ia[5] * D + lane]);
        float v6 = bf2f(feat[(size_t)ia[6] * D + lane]);
        float v7 = bf2f(feat[(size_t)ia[7] * D + lane]);
        float v8 = bf2f(feat[(size_t)ib[0] * D + lane]);
        float v9 = bf2f(feat[(size_t)ib[1] * D + lane]);
        float va = bf2f(feat[(size_t)ib[2] * D + lane]);
        float vb = bf2f(feat[(size_t)ib[3] * D + lane]);
        float vc = bf2f(feat[(size_t)ib[4] * D + lane]);
        float vd = bf2f(feat[(size_t)ib[5] * D + lane]);
        float ve = bf2f(feat[(size_t)ib[6] * D + lane]);
        float vf = bf2f(feat[(size_t)ib[7] * D + lane]);
        acc += (((v0 + v1) + (v2 + v3)) + ((v4 + v5) + (v6 + v7)))
             + (((v8 + v9) + (va + vb)) + ((vc + vd) + (ve + vf)));
    }
    outp[(size_t)n * D + lane] = f2bf(acc);
}

// ---------------------------------------------------------------------------
// MLP layer 1 via MFMA (verified m89/m91 layouts), bf16 out to h1.
// ---------------------------------------------------------------------------
__global__ __launch_bounds__(256) void mlp_kernel(
    const unsigned short* __restrict__ feat,
    const unsigned short* __restrict__ wAb,
    const float*          __restrict__ bA,
    const unsigned short* __restrict__ wBb,
    const float*          __restrict__ bB,
    unsigned short*       __restrict__ outp)
{
    __shared__ __align__(16) unsigned short st[4][16 * STP];

    const int wv   = threadIdx.x >> 6;
    const int lane = threadIdx.x & 63;
    const int quad = lane >> 4;
    const int col  = lane & 15;

    const int n0 = (blockIdx.x * 4 + wv) * 16;
    if (n0 >= N_NODES) return;

    float bAl[4], bBl[4];
#pragma unroll
    for (int t = 0; t < 4; ++t) {
        bAl[t] = bA[t * 16 + col];
        bBl[t] = bB[t * 16 + col];
    }

    short8 WA[4][2], WB[4][2];
#pragma unroll
    for (int t = 0; t < 4; ++t)
#pragma unroll
        for (int k = 0; k < 2; ++k) {
            WA[t][k] = *reinterpret_cast<const short8*>(
                wAb + (t * 16 + col) * D + k * 32 + quad * 8);
            WB[t][k] = *reinterpret_cast<const short8*>(
                wBb + (t * 16 + col) * D + k * 32 + quad * 8);
        }

    short8 A0 = *reinterpret_cast<const short8*>(
        feat + (size_t)(n0 + col) * D + 0 * 32 + quad * 8);
    short8 A1 = *reinterpret_cast<const short8*>(
        feat + (size_t)(n0 + col) * D + 1 * 32 + quad * 8);

    unsigned short* stw = &st[wv][0];

#pragma unroll
    for (int t = 0; t < 4; ++t) {
        floatx4 c = {0.0f, 0.0f, 0.0f, 0.0f};
        c = __builtin_amdgcn_mfma_f32_16x16x32_bf16(A0, WA[t][0], c, 0, 0, 0);
        c = __builtin_amdgcn_mfma_f32_16x16x32_bf16(A1, WA[t][1], c, 0, 0, 0);
#pragma unroll
        for (int r = 0; r < 4; ++r) {
            float v = fmaxf(c[r] + bAl[t], 0.0f);
            stw[(quad * 4 + r) * STP + t * 16 + col] = f2bf(v);
        }
    }

    short8 T0 = *reinterpret_cast<const short8*>(stw + col * STP + 0 * 32 + quad * 8);
    short8 T1 = *reinterpret_cast<const short8*>(stw + col * STP + 1 * 32 + quad * 8);

#pragma unroll
    for (int t = 0; t < 4; ++t) {
        floatx4 c = {0.0f, 0.0f, 0.0f, 0.0f};
        c = __builtin_amdgcn_mfma_f32_16x16x32_bf16(T0, WB[t][0], c, 0, 0, 0);
        c = __builtin_amdgcn_mfma_f32_16x16x32_bf16(T1, WB[t][1], c, 0, 0, 0);
#pragma unroll
        for (int r = 0; r < 4; ++r) {
            float v = fmaxf(c[r] + bBl[t], 0.0f);
            outp[(size_t)(n0 + quad * 4 + r) * D + t * 16 + col] = f2bf(v);
        }
    }
}

// ---------------------------------------------------------------------------
// MLP layer 2 + fused mean-pool numerator: output tile goes to LDS (fp32),
// then a per-block segmented reduction over sorted batch[] adds into
// psum[B,64] with one atomicAdd per (graph,dim) run. No f2 buffer.
// ---------------------------------------------------------------------------
__global__ __launch_bounds__(256) void mlp2_pool_kernel(
    const unsigned short* __restrict__ feat,   // gathered h (layer 2)
    const unsigned short* __restrict__ wAb,
    const float*          __restrict__ bA,
    const unsigned short* __restrict__ wBb,
    const float*          __restrict__ bB,
    const int*            __restrict__ batch,  // [N] sorted
    float*                __restrict__ psum)   // [B,64] zero-initialized
{
    __shared__ __align__(16) unsigned short st[4][16 * STP];
    __shared__ float pt[64][D + 1];            // block's 64-node output tile
    __shared__ int   sbatch[64];

    const int tid  = threadIdx.x;
    const int wv   = tid >> 6;
    const int lane = tid & 63;
    const int quad = lane >> 4;
    const int col  = lane & 15;

    const int bn0 = blockIdx.x * 64;           // block's first node
    const int n0  = bn0 + wv * 16;             // wave's first node
    const bool active = (n0 < N_NODES);

    if (tid < 64) {
        int n = bn0 + tid;
        sbatch[tid] = (n < N_NODES) ? batch[n] : -1;
    }

    if (active) {
        float bAl[4], bBl[4];
#pragma unroll
        for (int t = 0; t < 4; ++t) {
            bAl[t] = bA[t * 16 + col];
            bBl[t] = bB[t * 16 + col];
        }

        short8 WA[4][2], WB[4][2];
#pragma unroll
        for (int t = 0; t < 4; ++t)
#pragma unroll
            for (int k = 0; k < 2; ++k) {
                WA[t][k] = *reinterpret_cast<const short8*>(
                    wAb + (t * 16 + col) * D + k * 32 + quad * 8);
                WB[t][k] = *reinterpret_cast<const short8*>(
                    wBb + (t * 16 + col) * D + k * 32 + quad * 8);
            }

        short8 A0 = *reinterpret_cast<const short8*>(
            feat + (size_t)(n0 + col) * D + 0 * 32 + quad * 8);
        short8 A1 = *reinterpret_cast<const short8*>(
            feat + (size_t)(n0 + col) * D + 1 * 32 + quad * 8);

        unsigned short* stw = &st[wv][0];

#pragma unroll
        for (int t = 0; t < 4; ++t) {
            floatx4 c = {0.0f, 0.0f, 0.0f, 0.0f};
            c = __builtin_amdgcn_mfma_f32_16x16x32_bf16(A0, WA[t][0], c, 0, 0, 0);
            c = __builtin_amdgcn_mfma_f32_16x16x32_bf16(A1, WA[t][1], c, 0, 0, 0);
#pragma unroll
            for (int r = 0; r < 4; ++r) {
                float v = fmaxf(c[r] + bAl[t], 0.0f);
                stw[(quad * 4 + r) * STP + t * 16 + col] = f2bf(v);
            }
        }

        short8 T0 = *reinterpret_cast<const short8*>(stw + col * STP + 0 * 32 + quad * 8);
        short8 T1 = *reinterpret_cast<const short8*>(stw + col * STP + 1 * 32 + quad * 8);

#pragma unroll
        for (int t = 0; t < 4; ++t) {
            floatx4 c = {0.0f, 0.0f, 0.0f, 0.0f};
            c = __builtin_amdgcn_mfma_f32_16x16x32_bf16(T0, WB[t][0], c, 0, 0, 0);
            c = __builtin_amdgcn_mfma_f32_16x16x32_bf16(T1, WB[t][1], c, 0, 0, 0);
#pragma unroll
            for (int r = 0; r < 4; ++r) {
                float v = fmaxf(c[r] + bBl[t], 0.0f);
                pt[wv * 16 + quad * 4 + r][t * 16 + col] = v;
            }
        }
    } else {
        // inactive wave: zero its tile rows so the reduce sees zeros
#pragma unroll
        for (int r = 0; r < 4; ++r)
            pt[wv * 16 + quad * 4 + r][(lane & 15) * 4 + (lane >> 4)] = 0.0f;
        // fully zero the rows (16 cols per lane-iter)
        for (int c = 0; c < 4; ++c)
#pragma unroll
            for (int r = 0; r < 4; ++r)
                pt[wv * 16 + quad * 4 + r][c * 16 + col] = 0.0f;
    }
    __syncthreads();

    // segmented reduce: thread (q,d) sums rows q*16..q*16+15 of dim d,
    // flushing one atomicAdd per graph run (sorted batch => few runs).
    int q = tid >> 6;
    int d = tid & 63;
    float acc = 0.0f;
    int curg = sbatch[q * 16];
#pragma unroll
    for (int r = 0; r < 16; ++r) {
        int row = q * 16 + r;
        int g = sbatch[row];
        float v = pt[row][d];
        if (g != curg) {
            if (curg >= 0) atomicAdd(&psum[curg * D + d], acc);
            acc = 0.0f;
            curg = g;
        }
        acc += v;
    }
    if (curg >= 0) atomicAdd(&psum[curg * D + d], acc);
}

// ---------------------------------------------------------------------------
// Head: mean from psum + counts, single-step LSTM + FC + softmax.
// ---------------------------------------------------------------------------
__device__ __forceinline__ int lower_bound_dev(const int* a, int n, int v)
{
    int lo = 0, hi = n;
    while (lo < hi) {
        int m = (lo + hi) >> 1;
        if (a[m] < v) lo = m + 1; else hi = m;
    }
    return lo;
}

__device__ __forceinline__ float sigmoidf_(float x) { return 1.0f / (1.0f + expf(-x)); }

__global__ __launch_bounds__(512) void head_kernel(
    const float* __restrict__ psum,   // [B,64] pooled sums
    const int*   __restrict__ batch,  // [N]
    const float* __restrict__ w_ih,
    const float* __restrict__ w_hh,
    const float* __restrict__ b_ih,
    const float* __restrict__ b_hh,
    const float* __restrict__ fc_w,
    const float* __restrict__ fc_b,
    const float* __restrict__ h0,
    const float* __restrict__ c0,
    float*       __restrict__ out_probs,
    float*       __restrict__ out_h1,
    float*       __restrict__ out_c1)
{
    int b = blockIdx.x;
    int j = threadIdx.x;

    __shared__ float sp[D];
    __shared__ float sh[HL];
    __shared__ float gates[4 * HL];
    __shared__ float sh1[HL];
    __shared__ float slog[OUT];

    if (j < D) {
        int start = lower_bound_dev(batch, N_NODES, b);
        int end   = lower_bound_dev(batch, N_NODES, b + 1);
        sp[j] = psum[b * D + j] / fmaxf((float)(end - start), 1.0f);
    } else if (j < D + HL) {
        sh[j - D] = h0[b * HL + (j - D)];
    }
    __syncthreads();

    {
        float acc = b_ih[j] + b_hh[j];
#pragma unroll
        for (int k = 0; k < D; ++k)  acc = fmaf(sp[k], w_ih[j * D + k], acc);
#pragma unroll
        for (int k = 0; k < HL; ++k) acc = fmaf(sh[k], w_hh[j * HL + k], acc);
        gates[j] = acc;
    }
    __syncthreads();

    if (j < HL) {
        float ig = gates[j];
        float fg = gates[HL + j];
        float gg = gates[2 * HL + j];
        float og = gates[3 * HL + j];
        float c  = sigmoidf_(fg) * c0[b * HL + j] + sigmoidf_(ig) * tanhf(gg);
        float hv = sigmoidf_(og) * tanhf(c);
        out_c1[b * HL + j] = c;
        out_h1[b * HL + j] = hv;
        sh1[j] = hv;
    }
    __syncthreads();

    if (j < OUT) {
        float a = fc_b[j];
#pragma unroll
        for (int k = 0; k < HL; ++k) a = fmaf(sh1[k], fc_w[j * HL + k], a);
        slog[j] = a;
    }
    __syncthreads();

    if (j < OUT) {
        float m = -1e30f;
#pragma unroll
        for (int k = 0; k < OUT; ++k) m = fmaxf(m, slog[k]);
        float s = 0.0f;
#pragma unroll
        for (int k = 0; k < OUT; ++k) s += expf(slog[k] - m);
        out_probs[b * OUT + j] = expf(slog[j] - m) / s;
    }
}

// ---------------------------------------------------------------------------
extern "C" void kernel_launch(void* const* d_in, const int* in_sizes, int n_in,
                              void* d_out, int out_size, void* d_ws, size_t ws_size,
                              hipStream_t stream)
{
    const float* x     = (const float*)d_in[0];
    const int*   ei    = (const int*)  d_in[1];
    const int*   batch = (const int*)  d_in[2];
    const float* w1    = (const float*)d_in[3];
    const float* b1    = (const float*)d_in[4];
    const float* w2    = (const float*)d_in[5];
    const float* b2    = (const float*)d_in[6];
    const float* w3    = (const float*)d_in[7];
    const float* b3    = (const float*)d_in[8];
    const float* w4    = (const float*)d_in[9];
    const float* b4    = (const float*)d_in[10];
    const float* w_ih  = (const float*)d_in[11];
    const float* w_hh  = (const float*)d_in[12];
    const float* b_ih  = (const float*)d_in[13];
    const float* b_hh  = (const float*)d_in[14];
    const float* fc_w  = (const float*)d_in[15];
    const float* fc_b  = (const float*)d_in[16];
    const float* h0    = (const float*)d_in[17];
    const float* c0    = (const float*)d_in[18];

    // workspace layout (~22 MB); xb/h1 have N+16 rows (row ZROW = 0)
    const size_t NR = (size_t)N_NODES + 16;
    int* bincnt = (int*)d_ws;                                 // 256 ints
    int* cnt    = bincnt + 256;                               // N ints
    unsigned* binbuf = (unsigned*)(cnt + N_NODES);            // BINS*BCAP
    unsigned short* bucket = (unsigned short*)(binbuf + (size_t)BINS * BCAP);
    unsigned short* xb = bucket + (size_t)N_NODES * CAP;      // [NR,64] bf16
    unsigned short* g  = xb + NR * D;                         // [NR,64] gather out
    unsigned short* h1 = g  + NR * D;                         // [NR,64] mlp1 out
    unsigned short* wb = h1 + NR * D;                         // 4 x [64,64] bf16
    float* psum = (float*)(wb + 4 * D * D);                   // [B,64]

    float* out_probs = (float*)d_out;
    float* out_h1    = out_probs + B * OUT;
    float* out_c1    = out_h1 + B * HL;

    const int gb = N_NODES / 4;                      // 12500 (1 node/wave)
    const int mb = (N_NODES / 16 + 3) / 4;           // 782

    // ---- bincnt zero (1 KB) + fused prologue (binA || cvt || init) ----
    hipMemsetAsync(bincnt, 0, 256 * sizeof(int), stream);
    fused_pro_kernel<<<AB + CB + 1, 256, 0, stream>>>(
        ei, bincnt, binbuf, x, xb, w1, w2, w3, w4, wb, h1, psum);

    // ---- adjacency build phase B ----
    binB_kernel<<<BINS, 256, 0, stream>>>(bincnt, binbuf, cnt, bucket);

    // ---- layer 1 ----
    gather_kernel<<<gb, 256, 0, stream>>>(xb, cnt, bucket, g);
    mlp_kernel<<<mb, 256, 0, stream>>>(g, wb, b1, wb + 4096, b2, h1);

    // ---- layer 2 (MLP + fused pool) ----
    gather_kernel<<<gb, 256, 0, stream>>>(h1, cnt, bucket, g);
    mlp2_pool_kernel<<<mb, 256, 0, stream>>>(g, wb + 8192, b3, wb + 12288, b4,
                                             batch, psum);

    // ---- head ----
    head_kernel<<<B, 512, 0, stream>>>(psum, batch, w_ih, w_hh, b_ih, b_hh,
                                       fc_w, fc_b, h0, c0,
                                       out_probs, out_h1, out_c1);
}